// Round 10
// baseline (345.165 us; speedup 1.0000x reference)
//
#include <hip/hip_runtime.h>
#include <math.h>
#include <float.h>
#include <limits.h>

#define NBATCH 4
#define NPROP  4096
#define NCLS   91
#define NFG    90
#define NDET   100
#define CCAP   1024            // per-(image,class) candidate cap (never hit; validated R7-R9)
#define BN     (NBATCH * NPROP)
#define SCAP   16384           // >= max total survivors per image (90*100=9000), pow2

static __device__ __forceinline__ float clampf(float x, float lo, float hi) {
    return fminf(fmaxf(x, lo), hi);
}

// Decode + clip one (proposal, class) box. Identical arithmetic everywhere it is
// used -> bitwise-identical results (validated absmax 0.0, R1-R9).
static __device__ __forceinline__ void decode_box(int b, int np, int c,
    const float* __restrict__ props, const float* __restrict__ deltas,
    float W, float H, float& bx1, float& by1, float& bx2, float& by2)
{
    const float* pr = props + ((size_t)b * NPROP + np) * 4;
    const float x1 = pr[0], y1 = pr[1], x2 = pr[2], y2 = pr[3];
    const float w = x2 - x1, h = y2 - y1;
    const float cx = x1 + 0.5f * w, cy = y1 + 0.5f * h;
    const float* d = deltas + (((size_t)b * NPROP + np) * NCLS + c) * 4;
    const float BBC = 4.135166556742356f;   // log(1000/16)
    const float dx = d[0] / 10.0f;
    const float dy = d[1] / 10.0f;
    const float dw = fminf(d[2] / 5.0f, BBC);
    const float dh = fminf(d[3] / 5.0f, BBC);
    const float pcx = dx * w + cx;
    const float pcy = dy * h + cy;
    const float pw = expf(dw) * w;
    const float ph = expf(dh) * h;
    bx1 = clampf(pcx - 0.5f * pw, 0.0f, W);
    by1 = clampf(pcy - 0.5f * ph, 0.0f, H);
    bx2 = clampf(pcx + 0.5f * pw, 0.0f, W);
    by2 = clampf(pcy + 0.5f * ph, 0.0f, H);
}

// Kernel 1: per-proposal softmax stats (max, sum) + 91-bit FINAL candidate mask
// (score>0.05 AND size>=0.01 AND c>=1), via ballots -> 3 transposed u32 planes.
// All float expressions are bitwise identical to the ones class_nms recomputes.
// UNCHANGED from validated R9.
__global__ __launch_bounds__(256) void stats_mask_kernel(
    const float* __restrict__ logits, const float* __restrict__ props,
    const float* __restrict__ deltas, const int* __restrict__ imgsh,
    float2* __restrict__ stats, unsigned* __restrict__ mask)
{
    const int wavei = threadIdx.x >> 6;
    const int lane  = threadIdx.x & 63;
    const int p = blockIdx.x * 4 + wavei;          // 0 .. B*N-1
    const int b = p >> 12;
    const int np = p & (NPROP - 1);
    const float* lrow = logits + (size_t)p * NCLS;

    const float a  = lrow[lane];
    const float a2 = (lane + 64 < NCLS) ? lrow[lane + 64] : -INFINITY;

    float m = fmaxf(a, a2);                        // level s=64
    #pragma unroll
    for (int s = 32; s > 0; s >>= 1) m = fmaxf(m, __shfl_down(m, s));
    m = __shfl(m, 0);

    const float e0 = expf(a - m);
    const float e1 = (lane + 64 < NCLS) ? expf(a2 - m) : 0.0f;
    float sum = e0 + e1;                           // level s=64
    #pragma unroll
    for (int s = 32; s > 0; s >>= 1) sum += __shfl_down(sum, s);
    sum = __shfl(sum, 0);

    const float W = (float)imgsh[b * 2 + 1];
    const float H = (float)imgsh[b * 2 + 0];

    bool pass0 = ((e0 / sum) > 0.05f) && (lane >= 1);     // class = lane (skip bg 0)
    if (pass0) {
        float bx1, by1, bx2, by2;
        decode_box(b, np, lane, props, deltas, W, H, bx1, by1, bx2, by2);
        pass0 = ((bx2 - bx1) >= 0.01f) && ((by2 - by1) >= 0.01f);
    }
    bool pass1 = ((e1 / sum) > 0.05f);                    // class = lane+64 (<= 90)
    if (pass1) {
        float bx1, by1, bx2, by2;
        decode_box(b, np, lane + 64, props, deltas, W, H, bx1, by1, bx2, by2);
        pass1 = ((bx2 - bx1) >= 0.01f) && ((by2 - by1) >= 0.01f);
    }

    const unsigned long long b0 = __ballot(pass0);        // classes 0..63
    const unsigned long long b1 = __ballot(pass1);        // classes 64..90

    if (lane == 0) {
        stats[p] = make_float2(m, sum);
        mask[p]          = (unsigned)b0;           // plane 0: classes  0..31
        mask[BN + p]     = (unsigned)(b0 >> 32);   // plane 1: classes 32..63
        mask[2 * BN + p] = (unsigned)b1;           // plane 2: classes 64..90
    }
}

// One block (256 threads) per (image, class). UNCHANGED from validated R9.
__global__ __launch_bounds__(256) void class_nms_kernel(
    const float* __restrict__ logits, const float2* __restrict__ stats,
    const unsigned* __restrict__ mask,
    const float* __restrict__ props, const float* __restrict__ deltas,
    const int* __restrict__ imgsh,
    int* __restrict__ survCount, unsigned long long* __restrict__ svKeys)
{
    const int blk  = blockIdx.x;                   // 0..359
    const int b    = blk / NFG;
    const int cm1  = blk % NFG;                    // class - 1
    const int c    = cm1 + 1;
    const int t    = threadIdx.x;
    const int lane = t & 63;
    const int wid  = t >> 6;

    __shared__ unsigned long long sk[CCAP];        // 8 KB, sorted desc, 0 = pad
    __shared__ float4 sbox[CCAP];                  // 16 KB
    __shared__ int wtot[4];

    const float W = (float)imgsh[b * 2 + 1];
    const float H = (float)imgsh[b * 2 + 0];

    const unsigned* mp = mask + (size_t)(c >> 5) * BN + b * NPROP;
    const unsigned bit = 1u << (c & 31);

    // ---- pass 1: count final-mask hits (dense coalesced, no decode) ----
    int cnt = 0;
    #pragma unroll 4
    for (int np = t; np < NPROP; np += 256) cnt += (mp[np] & bit) ? 1 : 0;

    // ---- exclusive scan over 256 threads ----
    int v = cnt;
    #pragma unroll
    for (int s = 1; s < 64; s <<= 1) {
        const int u = __shfl_up(v, s);
        if (lane >= s) v += u;
    }
    if (lane == 63) wtot[wid] = v;
    __syncthreads();
    int base = 0;
    for (int w2 = 0; w2 < wid; ++w2) base += wtot[w2];
    int pos = base + v - cnt;                      // this thread's exclusive offset
    const int ntot = wtot[0] + wtot[1] + wtot[2] + wtot[3];
    const int n = min(ntot, CCAP);
    if (n == 0) { if (t == 0) survCount[blk] = 0; return; }

    // ---- pass 2: keys at deterministic positions ----
    for (int np = t; np < NPROP; np += 256) {
        if (!(mp[np] & bit)) continue;
        const int p = b * NPROP + np;
        const float lg = logits[(size_t)p * NCLS + c];
        const float2 st = stats[p];
        const float score = expf(lg - st.x) / st.y;   // bitwise = kernel-1 value
        const unsigned flat = (unsigned)(np * NFG + cm1);
        const unsigned long long key =
            ((unsigned long long)__float_as_uint(score) << 32) | (unsigned)(~flat);
        if (pos < CCAP) sk[pos] = key;
        ++pos;
    }
    __syncthreads();

    // ---- bitonic sort descending on [0, P) ----
    int P = 1; while (P < n) P <<= 1;              // pow2 pad, <= 1024
    for (int i = n + t; i < P; i += 256) sk[i] = 0ULL;

    for (unsigned kk = 2; kk <= (unsigned)P; kk <<= 1) {
        for (unsigned jj = kk >> 1; jj > 0; jj >>= 1) {
            __syncthreads();
            for (unsigned i = t; i < (unsigned)P; i += 256) {
                const unsigned ixj = i ^ jj;
                if (ixj > i) {
                    const unsigned long long x = sk[i], y = sk[ixj];
                    const bool up = ((i & kk) == 0);       // descending when up
                    if (up ? (x < y) : (x > y)) { sk[i] = y; sk[ixj] = x; }
                }
            }
        }
    }
    __syncthreads();

    // ---- decode boxes ONCE for sorted candidates ----
    for (int i = t; i < n; i += 256) {
        const unsigned flat = ~(unsigned)sk[i];
        const int np = flat / NFG;                 // flat % NFG == cm1 by construction
        float bx1, by1, bx2, by2;
        decode_box(b, np, c, props, deltas, W, H, bx1, by1, bx2, by2);
        sbox[i] = make_float4(bx1, by1, bx2, by2);
    }
    __syncthreads();

    // ---- wave-0 greedy sweep: survivors in registers, prefetched, branchless ----
    if (t >= 64) return;
    float4 own0 = make_float4(0.f, 0.f, 0.f, 0.f);
    float4 own1 = make_float4(0.f, 0.f, 0.f, 0.f);
    int ns = 0;
    unsigned long long kcur = sk[0];
    float4 bcur = sbox[0];
    for (int i = 0; i < n && ns < NDET; ++i) {
        const unsigned long long key = kcur;
        const float4 Q = bcur;
        const int j = i + 1;
        if (j < n) { kcur = sk[j]; bcur = sbox[j]; }       // prefetch next (hides LDS lat)
        const float aq = (Q.z - Q.x) * (Q.w - Q.y);
        const float iw0 = fmaxf(fminf(own0.z, Q.z) - fmaxf(own0.x, Q.x), 0.0f);
        const float ih0 = fmaxf(fminf(own0.w, Q.w) - fmaxf(own0.y, Q.y), 0.0f);
        const float in0 = iw0 * ih0;
        const float as0 = (own0.z - own0.x) * (own0.w - own0.y);
        const float iw1 = fmaxf(fminf(own1.z, Q.z) - fmaxf(own1.x, Q.x), 0.0f);
        const float ih1 = fmaxf(fminf(own1.w, Q.w) - fmaxf(own1.y, Q.y), 0.0f);
        const float in1 = iw1 * ih1;
        const float as1 = (own1.z - own1.x) * (own1.w - own1.y);
        const bool sup = (in0 / (as0 + aq - in0) > 0.5f) ||
                         (in1 / (as1 + aq - in1) > 0.5f);
        if (!__any(sup)) {
            if (lane == (ns & 63)) { if (ns < 64) own0 = Q; else own1 = Q; }
            if (lane == 0) svKeys[(size_t)blk * NDET + ns] = key;
            ++ns;
        }
    }
    if (t == 0) survCount[blk] = ns;
}

// One block (1024 threads) per image. Concatenate all per-class survivor keys,
// bitonic-sort the union descending (throughput-parallel, ~70-105 barrier
// phases), take L[0..99] = exact top-100 in (score desc, idx asc) order,
// decode outputs. Replaces the latency-bound 100-round serial merge.
__global__ __launch_bounds__(1024) void select_kernel(
    const int* __restrict__ survCount, const unsigned long long* __restrict__ svKeys,
    const float* __restrict__ props, const float* __restrict__ deltas,
    const int* __restrict__ imgsh, float* __restrict__ out)
{
    const int b = blockIdx.x;
    const int t = threadIdx.x;
    __shared__ unsigned long long L[SCAP];         // 128 KB
    __shared__ int offs[NFG + 1];

    if (t == 0) {
        int acc = 0;
        for (int c2 = 0; c2 < NFG; ++c2) { offs[c2] = acc; acc += survCount[b * NFG + c2]; }
        offs[NFG] = acc;
    }

    float* oB = out + (size_t)b * NDET * 4;
    float* oS = out + (size_t)NBATCH * NDET * 4 + (size_t)b * NDET;
    float* oL = out + (size_t)NBATCH * NDET * 5 + (size_t)b * NDET;
    if (t < NDET) {
        oB[t * 4 + 0] = 0.0f; oB[t * 4 + 1] = 0.0f;
        oB[t * 4 + 2] = 0.0f; oB[t * 4 + 3] = 0.0f;
        oS[t] = 0.0f; oL[t] = -1.0f;
    }
    __syncthreads();
    const int total = offs[NFG];                   // <= 9000

    // compacted load: one wave per class, strided
    for (int c2 = t >> 6; c2 < NFG; c2 += 16) {
        const int cbase = offs[c2];
        const int ccnt  = offs[c2 + 1] - cbase;
        const unsigned long long* src = svKeys + (size_t)(b * NFG + c2) * NDET;
        for (int s = (t & 63); s < ccnt; s += 64) L[cbase + s] = src[s];
    }
    int P = 1; while (P < total) P <<= 1;          // pow2 pad, <= SCAP
    for (int i = total + t; i < P; i += 1024) L[i] = 0ULL;

    // bitonic sort descending (keys unique, 0 sorts last)
    for (unsigned kk = 2; kk <= (unsigned)P; kk <<= 1) {
        for (unsigned jj = kk >> 1; jj > 0; jj >>= 1) {
            __syncthreads();
            for (unsigned i = t; i < (unsigned)P; i += 1024) {
                const unsigned ixj = i ^ jj;
                if (ixj > i) {
                    const unsigned long long x = L[i], y = L[ixj];
                    const bool up = ((i & kk) == 0);       // descending when up
                    if (up ? (x < y) : (x > y)) { L[i] = y; L[ixj] = x; }
                }
            }
        }
    }
    __syncthreads();

    if (t < NDET) {
        const unsigned long long key = (t < total) ? L[t] : 0ULL;
        if (key != 0ULL) {
            const unsigned flat = ~(unsigned)key;
            const float score = __uint_as_float((unsigned)(key >> 32));
            const int np = flat / NFG;
            const int c  = (int)(flat - (unsigned)np * NFG) + 1;
            const float W = (float)imgsh[b * 2 + 1];
            const float H = (float)imgsh[b * 2 + 0];
            float bx1, by1, bx2, by2;
            decode_box(b, np, c, props, deltas, W, H, bx1, by1, bx2, by2);
            oB[t * 4 + 0] = bx1; oB[t * 4 + 1] = by1;
            oB[t * 4 + 2] = bx2; oB[t * 4 + 3] = by2;
            oS[t] = score;
            oL[t] = (float)c;
        }
    }
}

extern "C" void kernel_launch(void* const* d_in, const int* in_sizes, int n_in,
                              void* d_out, int out_size, void* d_ws, size_t ws_size,
                              hipStream_t stream)
{
    const float* logits = (const float*)d_in[0];   // [B*N, 91]
    const float* deltas = (const float*)d_in[1];   // [B*N, 364]
    const float* props  = (const float*)d_in[2];   // [B, N, 4]
    const int*   imgsh  = (const int*)d_in[3];     // [B, 2]
    float* out = (float*)d_out;

    char* w = (char*)d_ws;
    float2* stats = (float2*)w;            w += (size_t)BN * sizeof(float2);       // 128 KB
    unsigned* mask = (unsigned*)w;         w += (size_t)3 * BN * sizeof(unsigned); // 192 KB
    int* survCount = (int*)w;              w += 4096;                              // 360 counts
    unsigned long long* svKeys = (unsigned long long*)w;
    w += (size_t)NBATCH * NFG * NDET * sizeof(unsigned long long);                 // 288 KB

    stats_mask_kernel<<<BN / 4, 256, 0, stream>>>(logits, props, deltas, imgsh, stats, mask);
    class_nms_kernel<<<NBATCH * NFG, 256, 0, stream>>>(
        logits, stats, mask, props, deltas, imgsh, survCount, svKeys);
    select_kernel<<<NBATCH, 1024, 0, stream>>>(
        survCount, svKeys, props, deltas, imgsh, out);
}

// Round 12
// 87.085 us; speedup vs baseline: 3.9636x; 3.9636x over previous
//
#include <hip/hip_runtime.h>
#include <math.h>
#include <float.h>
#include <limits.h>

#define NBATCH 4
#define NPROP  4096
#define NCLS   91
#define NFG    90
#define NDET   100
#define CCAP   1024            // per-(image,class) candidate cap (never hit; validated R7-R10)
#define BN     (NBATCH * NPROP)
#define SLOTS  (NFG * NDET)    // 9000 survivor slots per image
#define FCAP   16384           // fallback sort capacity (pow2 >= SLOTS)

static __device__ __forceinline__ float clampf(float x, float lo, float hi) {
    return fminf(fmaxf(x, lo), hi);
}

// Decode + clip one (proposal, class) box. Identical arithmetic everywhere it is
// used -> bitwise-identical results (validated absmax 0.0, R1-R10).
static __device__ __forceinline__ void decode_box(int b, int np, int c,
    const float* __restrict__ props, const float* __restrict__ deltas,
    float W, float H, float& bx1, float& by1, float& bx2, float& by2)
{
    const float* pr = props + ((size_t)b * NPROP + np) * 4;
    const float x1 = pr[0], y1 = pr[1], x2 = pr[2], y2 = pr[3];
    const float w = x2 - x1, h = y2 - y1;
    const float cx = x1 + 0.5f * w, cy = y1 + 0.5f * h;
    const float* d = deltas + (((size_t)b * NPROP + np) * NCLS + c) * 4;
    const float BBC = 4.135166556742356f;   // log(1000/16)
    const float dx = d[0] / 10.0f;
    const float dy = d[1] / 10.0f;
    const float dw = fminf(d[2] / 5.0f, BBC);
    const float dh = fminf(d[3] / 5.0f, BBC);
    const float pcx = dx * w + cx;
    const float pcy = dy * h + cy;
    const float pw = expf(dw) * w;
    const float ph = expf(dh) * h;
    bx1 = clampf(pcx - 0.5f * pw, 0.0f, W);
    by1 = clampf(pcy - 0.5f * ph, 0.0f, H);
    bx2 = clampf(pcx + 0.5f * pw, 0.0f, W);
    by2 = clampf(pcy + 0.5f * ph, 0.0f, H);
}

// Block-wide exclusive scan over 1024 threads (wave shfl scan + wave totals).
// wtot must be 16 ints of LDS. Barriers inside; safe for repeated calls.
static __device__ __forceinline__ int block_excl_scan(int v, int t, int* wtot)
{
    const int lane = t & 63, wid = t >> 6;
    int inc = v;
    #pragma unroll
    for (int s = 1; s < 64; s <<= 1) {
        const int u = __shfl_up(inc, s);
        if (lane >= s) inc += u;
    }
    if (lane == 63) wtot[wid] = inc;
    __syncthreads();
    int base = 0;
    for (int w2 = 0; w2 < wid; ++w2) base += wtot[w2];
    __syncthreads();                 // protect wtot for the next call
    return base + inc - v;
}

// Kernel 1: per-proposal softmax stats (max, sum) + 91-bit FINAL candidate mask
// (score>0.05 AND size>=0.01 AND c>=1). UNCHANGED from validated R9/R10.
__global__ __launch_bounds__(256) void stats_mask_kernel(
    const float* __restrict__ logits, const float* __restrict__ props,
    const float* __restrict__ deltas, const int* __restrict__ imgsh,
    float2* __restrict__ stats, unsigned* __restrict__ mask)
{
    const int wavei = threadIdx.x >> 6;
    const int lane  = threadIdx.x & 63;
    const int p = blockIdx.x * 4 + wavei;          // 0 .. B*N-1
    const int b = p >> 12;
    const int np = p & (NPROP - 1);
    const float* lrow = logits + (size_t)p * NCLS;

    const float a  = lrow[lane];
    const float a2 = (lane + 64 < NCLS) ? lrow[lane + 64] : -INFINITY;

    float m = fmaxf(a, a2);                        // level s=64
    #pragma unroll
    for (int s = 32; s > 0; s >>= 1) m = fmaxf(m, __shfl_down(m, s));
    m = __shfl(m, 0);

    const float e0 = expf(a - m);
    const float e1 = (lane + 64 < NCLS) ? expf(a2 - m) : 0.0f;
    float sum = e0 + e1;                           // level s=64
    #pragma unroll
    for (int s = 32; s > 0; s >>= 1) sum += __shfl_down(sum, s);
    sum = __shfl(sum, 0);

    const float W = (float)imgsh[b * 2 + 1];
    const float H = (float)imgsh[b * 2 + 0];

    bool pass0 = ((e0 / sum) > 0.05f) && (lane >= 1);     // class = lane (skip bg 0)
    if (pass0) {
        float bx1, by1, bx2, by2;
        decode_box(b, np, lane, props, deltas, W, H, bx1, by1, bx2, by2);
        pass0 = ((bx2 - bx1) >= 0.01f) && ((by2 - by1) >= 0.01f);
    }
    bool pass1 = ((e1 / sum) > 0.05f);                    // class = lane+64 (<= 90)
    if (pass1) {
        float bx1, by1, bx2, by2;
        decode_box(b, np, lane + 64, props, deltas, W, H, bx1, by1, bx2, by2);
        pass1 = ((bx2 - bx1) >= 0.01f) && ((by2 - by1) >= 0.01f);
    }

    const unsigned long long b0 = __ballot(pass0);        // classes 0..63
    const unsigned long long b1 = __ballot(pass1);        // classes 64..90

    if (lane == 0) {
        stats[p] = make_float2(m, sum);
        mask[p]          = (unsigned)b0;           // plane 0: classes  0..31
        mask[BN + p]     = (unsigned)(b0 >> 32);   // plane 1: classes 32..63
        mask[2 * BN + p] = (unsigned)b1;           // plane 2: classes 64..90
    }
}

// One block (256 threads) per (image, class). R9-validated pipeline; only
// change: zero-fill unused svKeys slots (select now blind-reads all slots).
__global__ __launch_bounds__(256) void class_nms_kernel(
    const float* __restrict__ logits, const float2* __restrict__ stats,
    const unsigned* __restrict__ mask,
    const float* __restrict__ props, const float* __restrict__ deltas,
    const int* __restrict__ imgsh, unsigned long long* __restrict__ svKeys)
{
    const int blk  = blockIdx.x;                   // 0..359
    const int b    = blk / NFG;
    const int cm1  = blk % NFG;                    // class - 1
    const int c    = cm1 + 1;
    const int t    = threadIdx.x;
    const int lane = t & 63;
    const int wid  = t >> 6;

    __shared__ unsigned long long sk[CCAP];        // 8 KB, sorted desc, 0 = pad
    __shared__ float4 sbox[CCAP];                  // 16 KB
    __shared__ int wtot[4];

    const float W = (float)imgsh[b * 2 + 1];
    const float H = (float)imgsh[b * 2 + 0];

    const unsigned* mp = mask + (size_t)(c >> 5) * BN + b * NPROP;
    const unsigned bit = 1u << (c & 31);

    // ---- pass 1: count final-mask hits (dense coalesced, no decode) ----
    int cnt = 0;
    #pragma unroll 4
    for (int np = t; np < NPROP; np += 256) cnt += (mp[np] & bit) ? 1 : 0;

    // ---- exclusive scan over 256 threads ----
    int v = cnt;
    #pragma unroll
    for (int s = 1; s < 64; s <<= 1) {
        const int u = __shfl_up(v, s);
        if (lane >= s) v += u;
    }
    if (lane == 63) wtot[wid] = v;
    __syncthreads();
    int base = 0;
    for (int w2 = 0; w2 < wid; ++w2) base += wtot[w2];
    int pos = base + v - cnt;                      // this thread's exclusive offset
    const int ntot = wtot[0] + wtot[1] + wtot[2] + wtot[3];
    const int n = min(ntot, CCAP);
    if (n == 0) {
        for (int i = t; i < NDET; i += 256) svKeys[(size_t)blk * NDET + i] = 0ULL;
        return;
    }

    // ---- pass 2: keys at deterministic positions ----
    for (int np = t; np < NPROP; np += 256) {
        if (!(mp[np] & bit)) continue;
        const int p = b * NPROP + np;
        const float lg = logits[(size_t)p * NCLS + c];
        const float2 st = stats[p];
        const float score = expf(lg - st.x) / st.y;   // bitwise = kernel-1 value
        const unsigned flat = (unsigned)(np * NFG + cm1);
        const unsigned long long key =
            ((unsigned long long)__float_as_uint(score) << 32) | (unsigned)(~flat);
        if (pos < CCAP) sk[pos] = key;
        ++pos;
    }
    __syncthreads();

    // ---- bitonic sort descending on [0, P) ----
    int P = 1; while (P < n) P <<= 1;              // pow2 pad, <= 1024
    for (int i = n + t; i < P; i += 256) sk[i] = 0ULL;

    for (unsigned kk = 2; kk <= (unsigned)P; kk <<= 1) {
        for (unsigned jj = kk >> 1; jj > 0; jj >>= 1) {
            __syncthreads();
            for (unsigned i = t; i < (unsigned)P; i += 256) {
                const unsigned ixj = i ^ jj;
                if (ixj > i) {
                    const unsigned long long x = sk[i], y = sk[ixj];
                    const bool up = ((i & kk) == 0);       // descending when up
                    if (up ? (x < y) : (x > y)) { sk[i] = y; sk[ixj] = x; }
                }
            }
        }
    }
    __syncthreads();

    // ---- decode boxes ONCE for sorted candidates ----
    for (int i = t; i < n; i += 256) {
        const unsigned flat = ~(unsigned)sk[i];
        const int np = flat / NFG;                 // flat % NFG == cm1 by construction
        float bx1, by1, bx2, by2;
        decode_box(b, np, c, props, deltas, W, H, bx1, by1, bx2, by2);
        sbox[i] = make_float4(bx1, by1, bx2, by2);
    }
    __syncthreads();

    // ---- wave-0 greedy sweep: survivors in registers, prefetched, branchless ----
    if (t >= 64) return;
    float4 own0 = make_float4(0.f, 0.f, 0.f, 0.f);
    float4 own1 = make_float4(0.f, 0.f, 0.f, 0.f);
    int ns = 0;
    unsigned long long kcur = sk[0];
    float4 bcur = sbox[0];
    for (int i = 0; i < n && ns < NDET; ++i) {
        const unsigned long long key = kcur;
        const float4 Q = bcur;
        const int j = i + 1;
        if (j < n) { kcur = sk[j]; bcur = sbox[j]; }       // prefetch next (hides LDS lat)
        const float aq = (Q.z - Q.x) * (Q.w - Q.y);
        const float iw0 = fmaxf(fminf(own0.z, Q.z) - fmaxf(own0.x, Q.x), 0.0f);
        const float ih0 = fmaxf(fminf(own0.w, Q.w) - fmaxf(own0.y, Q.y), 0.0f);
        const float in0 = iw0 * ih0;
        const float as0 = (own0.z - own0.x) * (own0.w - own0.y);
        const float iw1 = fmaxf(fminf(own1.z, Q.z) - fmaxf(own1.x, Q.x), 0.0f);
        const float ih1 = fmaxf(fminf(own1.w, Q.w) - fmaxf(own1.y, Q.y), 0.0f);
        const float in1 = iw1 * ih1;
        const float as1 = (own1.z - own1.x) * (own1.w - own1.y);
        const bool sup = (in0 / (as0 + aq - in0) > 0.5f) ||
                         (in1 / (as1 + aq - in1) > 0.5f);
        if (!__any(sup)) {
            if (lane == (ns & 63)) { if (ns < 64) own0 = Q; else own1 = Q; }
            if (lane == 0) svKeys[(size_t)blk * NDET + ns] = key;
            ++ns;
        }
    }
    // zero-fill unused slots (wave 0, deterministic)
    for (int i = ns + lane; i < NDET; i += 64) svKeys[(size_t)blk * NDET + i] = 0ULL;
}

// One block (1024 threads) per image. Radix-select top-100 of the <=9000
// survivor keys: 12-bit-prefix histogram -> threshold digit T at rank 100 ->
// deterministic compaction of {digit >= T} (typically ~100-300) -> small
// bitonic sort -> F[0..99] is the exact top-100 in (score desc, idx asc) order.
// Fallback (compact > 2048, pathological): sort all nonzero keys (correct).
__global__ __launch_bounds__(1024) void select_kernel(
    const unsigned long long* __restrict__ svKeys,
    const float* __restrict__ props, const float* __restrict__ deltas,
    const int* __restrict__ imgsh, float* __restrict__ out)
{
    const int b = blockIdx.x;
    const int t = threadIdx.x;
    __shared__ unsigned long long F[FCAP];         // 128 KB (sort buffer)
    __shared__ int hist[4096];                     // 16 KB
    __shared__ int wtot[16];
    __shared__ int s_T, s_above, s_total;

    if (t == 0) { s_T = -1; s_above = 0; s_total = 0; }
    #pragma unroll
    for (int j = 0; j < 4; ++j) hist[t + j * 1024] = 0;

    // ---- load 9 slots/thread into registers (static indexing) ----
    const unsigned long long* src = svKeys + (size_t)b * SLOTS;
    unsigned long long keys[9];
    #pragma unroll
    for (int j = 0; j < 9; ++j) {
        const int s = t + j * 1024;
        keys[j] = (s < SLOTS) ? src[s] : 0ULL;
    }
    __syncthreads();

    // ---- histogram top-12-bit prefix (monotonic in key order) ----
    #pragma unroll
    for (int j = 0; j < 9; ++j) {
        if (keys[j] != 0ULL) atomicAdd(&hist[(unsigned)(keys[j] >> 52)], 1);
    }
    __syncthreads();

    // ---- find threshold digit T: cumAbove < NDET <= cumAbove + hist[T] ----
    // thread t owns bucket group (descending): base = (1023 - t) * 4
    {
        const int gbase = (1023 - t) * 4;
        const int s0 = hist[gbase] + hist[gbase + 1] + hist[gbase + 2] + hist[gbase + 3];
        const int pre = block_excl_scan(s0, t, wtot);   // counts in all higher buckets
        int acc = pre;
        for (int d = gbase + 3; d >= gbase; --d) {
            const int h = hist[d];
            if (acc < NDET && acc + h >= NDET) { s_T = d; s_above = acc; }  // unique
            acc += h;
        }
        if (t == 1023) s_total = acc;              // lowest group finishes the total
    }
    __syncthreads();

    const int T = s_T;
    const int total = s_total;
    const int n2 = (T < 0) ? total : (s_above + hist[T]);
    const bool fast = (n2 <= 2048);

    // ---- deterministic compaction (two-pass, registers -> F) ----
    int mycnt = 0;
    #pragma unroll
    for (int j = 0; j < 9; ++j) {
        const unsigned long long k = keys[j];
        const bool m = (k != 0ULL) && (fast ? (T < 0 || (int)(k >> 52) >= T) : true);
        mycnt += m ? 1 : 0;
    }
    int off = block_excl_scan(mycnt, t, wtot);
    #pragma unroll
    for (int j = 0; j < 9; ++j) {
        const unsigned long long k = keys[j];
        const bool m = (k != 0ULL) && (fast ? (T < 0 || (int)(k >> 52) >= T) : true);
        if (m) F[off++] = k;
    }
    const int nsort = fast ? n2 : total;

    int P = 128; while (P < nsort) P <<= 1;        // pow2 pad, >= 128, <= FCAP
    for (int i = nsort + t; i < P; i += 1024) F[i] = 0ULL;

    // ---- bitonic sort descending on F[0, P) ----
    for (unsigned kk = 2; kk <= (unsigned)P; kk <<= 1) {
        for (unsigned jj = kk >> 1; jj > 0; jj >>= 1) {
            __syncthreads();
            for (unsigned i = t; i < (unsigned)P; i += 1024) {
                const unsigned ixj = i ^ jj;
                if (ixj > i) {
                    const unsigned long long x = F[i], y = F[ixj];
                    const bool up = ((i & kk) == 0);       // descending when up
                    if (up ? (x < y) : (x > y)) { F[i] = y; F[ixj] = x; }
                }
            }
        }
    }
    __syncthreads();

    // ---- outputs ----
    float* oB = out + (size_t)b * NDET * 4;
    float* oS = out + (size_t)NBATCH * NDET * 4 + (size_t)b * NDET;
    float* oL = out + (size_t)NBATCH * NDET * 5 + (size_t)b * NDET;
    if (t < NDET) {
        const unsigned long long key = F[t];       // P >= 128 > NDET, zero-padded
        if (key != 0ULL) {
            const unsigned flat = ~(unsigned)key;
            const float score = __uint_as_float((unsigned)(key >> 32));
            const int np = flat / NFG;
            const int c  = (int)(flat - (unsigned)np * NFG) + 1;
            const float W = (float)imgsh[b * 2 + 1];
            const float H = (float)imgsh[b * 2 + 0];
            float bx1, by1, bx2, by2;
            decode_box(b, np, c, props, deltas, W, H, bx1, by1, bx2, by2);
            oB[t * 4 + 0] = bx1; oB[t * 4 + 1] = by1;
            oB[t * 4 + 2] = bx2; oB[t * 4 + 3] = by2;
            oS[t] = score;
            oL[t] = (float)c;
        } else {
            oB[t * 4 + 0] = 0.0f; oB[t * 4 + 1] = 0.0f;
            oB[t * 4 + 2] = 0.0f; oB[t * 4 + 3] = 0.0f;
            oS[t] = 0.0f; oL[t] = -1.0f;
        }
    }
}

extern "C" void kernel_launch(void* const* d_in, const int* in_sizes, int n_in,
                              void* d_out, int out_size, void* d_ws, size_t ws_size,
                              hipStream_t stream)
{
    const float* logits = (const float*)d_in[0];   // [B*N, 91]
    const float* deltas = (const float*)d_in[1];   // [B*N, 364]
    const float* props  = (const float*)d_in[2];   // [B, N, 4]
    const int*   imgsh  = (const int*)d_in[3];     // [B, 2]
    float* out = (float*)d_out;

    char* w = (char*)d_ws;
    float2* stats = (float2*)w;            w += (size_t)BN * sizeof(float2);       // 128 KB
    unsigned* mask = (unsigned*)w;         w += (size_t)3 * BN * sizeof(unsigned); // 192 KB
    unsigned long long* svKeys = (unsigned long long*)w;
    w += (size_t)NBATCH * SLOTS * sizeof(unsigned long long);                      // 288 KB

    stats_mask_kernel<<<BN / 4, 256, 0, stream>>>(logits, props, deltas, imgsh, stats, mask);
    class_nms_kernel<<<NBATCH * NFG, 256, 0, stream>>>(
        logits, stats, mask, props, deltas, imgsh, svKeys);
    select_kernel<<<NBATCH, 1024, 0, stream>>>(svKeys, props, deltas, imgsh, out);
}